// Round 11
// baseline (83.877 us; speedup 1.0000x reference)
//
#include <hip/hip_runtime.h>
#include <math.h>

// CapsuleLayer dynamic routing, factored (u_hat never materialized):
//   s[b,m,:] = ((Sum_n e_n in[b,n,:]) / (Sum_n e_n)) @ W[:,m,:], e_n = exp(logit)
//   logit linear in per-pass wv updates -> cumulative wv, no per-n state.
//   Pass 0 (uniform softmax) = plain column sum, S = 2048.
//
// Plateau evidence (R7/R8/R10 all ~31-35us): 3x re-read of inputs through
// L1/L2 with a dependent load->barrier->tail chain per pass; 2 blocks/CU
// can't hide ~300cyc L2 latency of 16 loads/lane/pass.
// R11: INPUTS LIVE IN REGISTERS. Lane's working set = its 16 float4s (64
// VGPR), loaded once (pass 0), reused passes 1-2 -> those passes are pure
// VALU/DPP/exp, zero loads. launch_bounds(512,2) -> 128-reg budget
// (measured compiler rule VGPR = 256/min_waves, R1-R5); state ~110 fits.
// HW residency at ~128 VGPR: 4 waves/EU = 16 waves/CU = 2 blocks/CU (m69).
// Kept from R10 (all measured wins): dense loads (lane=(row,c4), 1 instr =
// 64 distinct 64B lines), quad dot via DPP quad_perm (VALU), harvest via
// row_shl:4/8 only (NO xor16/32 shfl - __shfl is ds_bpermute, DS pipe),
// 32 sub-partials in red[32][69] (conflict-free stores), single-wave tail,
// 2 barriers/pass (5 total), pass-0 harvest = 4 values, W in LDS stride 65,
// b = bx&63 pins batch to XCD b%8.

#define TPB 512

typedef float vf2 __attribute__((ext_vector_type(2)));

// x + dpp_shuffled(x); bound_ctrl=true -> out-of-pattern lanes contribute 0
#define DPP_ADDF(x, ctrl) \
    ((x) + __int_as_float(__builtin_amdgcn_update_dpp( \
        0, __float_as_int(x), (ctrl), 0xF, 0xF, true)))
// quad_perm xor1 = 0xB1, xor2 = 0x4E; row_shl:4 = 0x104, row_shl:8 = 0x108

__global__ __launch_bounds__(TPB, 2)
void capsule_routing_kernel(const float* __restrict__ in,
                            const float* __restrict__ W,
                            float* __restrict__ out)
{
    __shared__ float red[32 * 69];   // [wave*4+rowof16][m*17 + {S, xc[16]}]
    __shared__ float cum[64];        // cumulative wv[tmi][d]
    __shared__ float w_lds[16 * 65]; // W[d][tmi*16+c], stride 65

    const int tid = threadIdx.x;
    const int w   = tid >> 6;        // 0..7
    const int l   = tid & 63;
    const int c4  = l & 3;           // dim-quarter of row
    const int rg  = l >> 4;          // row-of-16 within wave (0..3)
    const int b   = blockIdx.x & 63;
    const int m0  = (blockIdx.x >> 6) << 2;

    // dense: lane l reads float4 #(w*1024 + g*64 + l); wave w owns rows
    // [w*256, w*256+256), g = 0..15
    const float4* __restrict__ inb4 =
        (const float4*)(in + ((size_t)b << 15)) + ((w << 10) + l);

    // stage W[:, m0:m0+4, :] (1024 floats) -> LDS, stride-65 rows.
    // Ordered before first use by pass-0's red barrier.
    #pragma unroll
    for (int k = 0; k < 2; ++k) {
        const int idx = tid + k * TPB;
        const int d = idx >> 6, r = idx & 63;
        w_lds[d * 65 + r] = W[(d << 9) + (m0 << 4) + r];
    }

    float4 f[16];                    // THE input slice: persistent, 64 VGPRs
    float  cwv = 0.f;                // tail-wave cumulative wv (lane = tmi,tc)

    for (int pass = 0; pass < 3; ++pass) {
        vf2 wva[4], wvb[4];
        if (pass) {
            const float4* cp = (const float4*)cum;   // 16-way broadcast reads
            #pragma unroll
            for (int m = 0; m < 4; ++m) {
                const float4 q = cp[(m << 2) + c4];  // cum[m*16 + c4*4 ..+3]
                wva[m].x = q.x; wva[m].y = q.y;
                wvb[m].x = q.z; wvb[m].y = q.w;
            }
        }

        vf2 xa[4], xb[4];
        float S[4];
        #pragma unroll
        for (int m = 0; m < 4; ++m) {
            xa[m].x = 0.f; xa[m].y = 0.f;
            xb[m].x = 0.f; xb[m].y = 0.f;
            S[m] = 0.f;
        }

        #pragma unroll
        for (int g = 0; g < 16; ++g) {
            if (pass == 0) f[g] = inb4[g << 6];      // only loads in the kernel
            vf2 fa, fb;
            fa.x = f[g].x; fa.y = f[g].y; fb.x = f[g].z; fb.y = f[g].w;
            if (pass) {
                #pragma unroll
                for (int m = 0; m < 4; ++m) {
                    vf2 t = fa * wva[m] + fb * wvb[m];   // pk_mul + pk_fma
                    float d = t.x + t.y;
                    d = DPP_ADDF(d, 0xB1);               // quad-sum (VALU)
                    d = DPP_ADDF(d, 0x4E);
                    const float e = __expf(d);           // quad-uniform
                    S[m] += e;
                    xa[m] += fa * e;
                    xb[m] += fb * e;
                }
            } else {                                     // e = 1, m-independent
                xa[0] += fa; xb[0] += fb;
            }
        }

        // harvest: row_shl:4 + row_shl:8 (VALU DPP) -> lanes 0..3 of each
        // row-of-16 hold that row-of-16's c4-group sums; 16 lanes/wave write
        // sub-partials, tail merges all 32. No cross-row shuffle.
        const int pbase = ((w << 2) + rg) * 69;
        if (pass) {
            float vals[20] = { xa[0].x, xa[0].y, xb[0].x, xb[0].y,
                               xa[1].x, xa[1].y, xb[1].x, xb[1].y,
                               xa[2].x, xa[2].y, xb[2].x, xb[2].y,
                               xa[3].x, xa[3].y, xb[3].x, xb[3].y,
                               S[0], S[1], S[2], S[3] };
            #pragma unroll
            for (int v = 0; v < 20; ++v) {
                float x = vals[v];
                x = DPP_ADDF(x, 0x104);   // lane i += lane i+4
                x = DPP_ADDF(x, 0x108);   // lane i += lane i+8
                vals[v] = x;
            }
            if ((l & 15) < 4) {           // l&15 == c4
                #pragma unroll
                for (int m = 0; m < 4; ++m) {
                    #pragma unroll
                    for (int j = 0; j < 4; ++j)
                        red[pbase + m * 17 + 1 + (c4 << 2) + j] = vals[(m << 2) + j];
                }
                if ((l & 15) == 0) {
                    #pragma unroll
                    for (int m = 0; m < 4; ++m)
                        red[pbase + m * 17] = vals[16 + m];
                }
            }
        } else {
            float vals[4] = { xa[0].x, xa[0].y, xb[0].x, xb[0].y };
            #pragma unroll
            for (int v = 0; v < 4; ++v) {
                float x = vals[v];
                x = DPP_ADDF(x, 0x104);
                x = DPP_ADDF(x, 0x108);
                vals[v] = x;
            }
            if ((l & 15) < 4) {
                #pragma unroll
                for (int j = 0; j < 4; ++j)
                    red[pbase + 1 + (c4 << 2) + j] = vals[j];
            }
        }
        __syncthreads();                  // red ready (also orders W staging)

        // ---- tail: wave 0 only. lane = (tmi = l>>4, tc = l&15) ----
        if (w == 0) {
            const int tmi = rg;           // l>>4
            const int tc  = l & 15;
            float Stot = 0.f, xtot = 0.f;
            if (pass) {
                #pragma unroll
                for (int p = 0; p < 32; ++p) {
                    Stot += red[p * 69 + tmi * 17];
                    xtot += red[p * 69 + tmi * 17 + 1 + tc];
                }
            } else {
                Stot = 2048.f;
                #pragma unroll
                for (int p = 0; p < 32; ++p)
                    xtot += red[p * 69 + 1 + tc];   // m0 slots; same for all m
            }
            // s(tmi,tc) = (1/S) Sum_d xtot(tmi,d) * W[d][tmi*16+tc]
            float s = 0.f;
            #pragma unroll
            for (int d = 0; d < 16; ++d)
                s += __shfl(xtot, (tmi << 4) + d) * w_lds[d * 65 + (tmi << 4) + tc];
            s /= Stot;
            float n2 = s * s;
            n2 += __shfl_xor(n2, 1);
            n2 += __shfl_xor(n2, 2);
            n2 += __shfl_xor(n2, 4);
            n2 += __shfl_xor(n2, 8);
            const float nr = sqrtf(n2);
            const float v  = s * (n2 / (1.f + n2)) / (nr + 1e-7f);
            if (pass < 2) {
                float wvv = 0.f;          // wv(tmi, d=tc)
                #pragma unroll
                for (int c2 = 0; c2 < 16; ++c2)
                    wvv += w_lds[tc * 65 + (tmi << 4) + c2] * __shfl(v, (tmi << 4) + c2);
                cwv += wvv;               // accumulates across passes
                cum[(tmi << 4) + tc] = cwv;
            } else {
                out[((size_t)b << 9) + ((m0 + tmi) << 4) + tc] = v;
            }
        }
        if (pass < 2) __syncthreads();    // cum ready; red free for next pass
    }
}

extern "C" void kernel_launch(void* const* d_in, const int* in_sizes, int n_in,
                              void* d_out, int out_size, void* d_ws, size_t ws_size,
                              hipStream_t stream) {
    (void)in_sizes; (void)n_in; (void)d_ws; (void)ws_size; (void)out_size;
    const float* in = (const float*)d_in[0];
    const float* W  = (const float*)d_in[1];
    float* out = (float*)d_out;
    hipLaunchKernelGGL(capsule_routing_kernel, dim3(512), dim3(TPB), 0, stream,
                       in, W, out);
}